// Round 1
// baseline (178.169 us; speedup 1.0000x reference)
//
#include <hip/hip_runtime.h>
#include <math.h>

#define NBINS 256

__device__ __forceinline__ int quant_idx(float s) {
    // reference: clip(floor((s+1)/2*255), 0, 255)
    float t = floorf((s + 1.0f) * 0.5f * 255.0f);
    t = fminf(fmaxf(t, 0.0f), 255.0f);
    return (int)t;
}

// Pass 1: histogram (per-wave LDS privatized) + optional packed-u8 idx store.
template <bool STORE_IDX>
__global__ __launch_bounds__(256) void hist_kernel(
    const float* __restrict__ src, unsigned int* __restrict__ g_hist,
    unsigned int* __restrict__ idx4_out, int n4, int n) {
    __shared__ unsigned int lh[4][NBINS];
    const int tid = threadIdx.x;
    const int wave = tid >> 6;
    for (int i = tid; i < 4 * NBINS; i += blockDim.x)
        ((unsigned int*)lh)[i] = 0u;
    __syncthreads();

    const int stride = gridDim.x * blockDim.x;
    const float4* src4 = (const float4*)src;
    for (int i = blockIdx.x * blockDim.x + tid; i < n4; i += stride) {
        float4 v = src4[i];
        int i0 = quant_idx(v.x);
        int i1 = quant_idx(v.y);
        int i2 = quant_idx(v.z);
        int i3 = quant_idx(v.w);
        atomicAdd(&lh[wave][i0], 1u);
        atomicAdd(&lh[wave][i1], 1u);
        atomicAdd(&lh[wave][i2], 1u);
        atomicAdd(&lh[wave][i3], 1u);
        if (STORE_IDX) {
            unsigned int packed = (unsigned int)i0 | ((unsigned int)i1 << 8) |
                                  ((unsigned int)i2 << 16) | ((unsigned int)i3 << 24);
            idx4_out[i] = packed;
        }
    }
    // tail (n not divisible by 4) — handled by one thread
    if (blockIdx.x == 0 && tid == 0) {
        for (int j = n4 * 4; j < n; ++j) {
            int b = quant_idx(src[j]);
            atomicAdd(&g_hist[b], 1u);
            if (STORE_IDX) ((unsigned char*)idx4_out)[j] = (unsigned char)b;
        }
    }
    __syncthreads();
    for (int b = tid; b < NBINS; b += blockDim.x) {
        unsigned int s = lh[0][b] + lh[1][b] + lh[2][b] + lh[3][b];
        if (s) atomicAdd(&g_hist[b], s);
    }
}

// Pass 2: one block of 256 threads builds the pre-scaled output LUT.
__global__ __launch_bounds__(256) void lut_kernel(
    const unsigned int* __restrict__ g_hist, float* __restrict__ lut) {
    __shared__ unsigned int h[NBINS];
    __shared__ unsigned int cum[NBINS];
    __shared__ float scdf[NBINS];
    __shared__ float ncdf[NBINS];
    const int t = threadIdx.x;
    h[t] = g_hist[t];
    __syncthreads();
    if (t == 0) {
        unsigned int c = 0;
        for (int i = 0; i < NBINS; ++i) { c += h[i]; cum[i] = c; }
    }
    __syncthreads();
    const float total = (float)cum[NBINS - 1];
    scdf[t] = (float)cum[t] / total;

    // linspace(-1,1,256): exact at both endpoints
    float x = ((float)t * 2.0f - 255.0f) / 255.0f;
    // norm.cdf(x, 0, 0.2) = 0.5*(1+erf(x/(0.2*sqrt(2))))
    float nc = 0.5f * (1.0f + erff(x * 3.5355339059327378f));
    ncdf[t] = nc;
    __syncthreads();
    const float norm = ncdf[NBINS - 1];
    __syncthreads();                 // everyone read norm before overwrite
    ncdf[t] = nc / norm;
    __syncthreads();

    // searchsorted side='left' == lower_bound
    float v = scdf[t];
    int lo = 0, hi = NBINS;
    while (lo < hi) {
        int m = (lo + hi) >> 1;
        if (ncdf[m] < v) lo = m + 1; else hi = m;
    }
    // pre-apply final rescale: out = r/255*2 - 1
    lut[t] = ((float)lo / 255.0f) * 2.0f - 1.0f;
}

// Pass 3a: gather via stored u8 indices.
__global__ __launch_bounds__(256) void gather_idx_kernel(
    const unsigned int* __restrict__ idx4, const float* __restrict__ lut,
    float4* __restrict__ out, int n4, int n, float* __restrict__ out_flat) {
    __shared__ float l[NBINS];
    for (int i = threadIdx.x; i < NBINS; i += blockDim.x) l[i] = lut[i];
    __syncthreads();
    const int stride = gridDim.x * blockDim.x;
    for (int i = blockIdx.x * blockDim.x + threadIdx.x; i < n4; i += stride) {
        unsigned int p = idx4[i];
        float4 o;
        o.x = l[p & 255u];
        o.y = l[(p >> 8) & 255u];
        o.z = l[(p >> 16) & 255u];
        o.w = l[p >> 24];
        out[i] = o;
    }
    if (blockIdx.x == 0 && threadIdx.x == 0) {
        const unsigned char* ib = (const unsigned char*)idx4;
        for (int j = n4 * 4; j < n; ++j) out_flat[j] = l[ib[j]];
    }
}

// Pass 3b fallback: recompute idx from source (no ws space).
__global__ __launch_bounds__(256) void gather_src_kernel(
    const float* __restrict__ src, const float* __restrict__ lut,
    float4* __restrict__ out, int n4, int n, float* __restrict__ out_flat) {
    __shared__ float l[NBINS];
    for (int i = threadIdx.x; i < NBINS; i += blockDim.x) l[i] = lut[i];
    __syncthreads();
    const int stride = gridDim.x * blockDim.x;
    const float4* src4 = (const float4*)src;
    for (int i = blockIdx.x * blockDim.x + threadIdx.x; i < n4; i += stride) {
        float4 v = src4[i];
        float4 o;
        o.x = l[quant_idx(v.x)];
        o.y = l[quant_idx(v.y)];
        o.z = l[quant_idx(v.z)];
        o.w = l[quant_idx(v.w)];
        out[i] = o;
    }
    if (blockIdx.x == 0 && threadIdx.x == 0) {
        for (int j = n4 * 4; j < n; ++j) out_flat[j] = l[quant_idx(src[j])];
    }
}

extern "C" void kernel_launch(void* const* d_in, const int* in_sizes, int n_in,
                              void* d_out, int out_size, void* d_ws, size_t ws_size,
                              hipStream_t stream) {
    const float* src = (const float*)d_in[0];
    const int n = in_sizes[0];
    const int n4 = n >> 2;

    unsigned int* hist = (unsigned int*)d_ws;                       // 1024 B
    float* lut = (float*)((char*)d_ws + 1024);                      // 1024 B
    unsigned int* idx4 = (unsigned int*)((char*)d_ws + 2048);       // n bytes
    const bool store_idx = ws_size >= (size_t)2048 + (size_t)n;

    hipMemsetAsync(hist, 0, NBINS * sizeof(unsigned int), stream);

    const dim3 block(256);
    const dim3 grid(2048);
    if (store_idx) {
        hist_kernel<true><<<grid, block, 0, stream>>>(src, hist, idx4, n4, n);
    } else {
        hist_kernel<false><<<grid, block, 0, stream>>>(src, hist, nullptr, n4, n);
    }
    lut_kernel<<<1, 256, 0, stream>>>(hist, lut);
    if (store_idx) {
        gather_idx_kernel<<<grid, block, 0, stream>>>(idx4, lut, (float4*)d_out,
                                                      n4, n, (float*)d_out);
    } else {
        gather_src_kernel<<<grid, block, 0, stream>>>(src, lut, (float4*)d_out,
                                                      n4, n, (float*)d_out);
    }
}

// Round 2
// 128.037 us; speedup vs baseline: 1.3915x; 1.3915x over previous
//
#include <hip/hip_runtime.h>
#include <math.h>

#define NBINS 256
#define HIST_BLOCKS 1024

typedef float vfloat4 __attribute__((ext_vector_type(4)));

__device__ __forceinline__ int quant_idx(float s) {
    // reference: clip(floor((s+1)/2*255), 0, 255)
    float t = floorf((s + 1.0f) * 0.5f * 255.0f);
    t = fminf(fmaxf(t, 0.0f), 255.0f);
    return (int)t;
}

// Pass 1: per-wave LDS histograms -> per-block partial histogram (plain
// stores, no global atomics, no init required) + packed-u8 idx store.
template <bool STORE_IDX>
__global__ __launch_bounds__(256) void hist_kernel(
    const float* __restrict__ src, unsigned int* __restrict__ partial,
    unsigned int* __restrict__ idx4_out, int n4, int n) {
    __shared__ unsigned int lh[4][NBINS];
    const int tid = threadIdx.x;
    const int wave = tid >> 6;
    for (int i = tid; i < 4 * NBINS; i += 256)
        ((unsigned int*)lh)[i] = 0u;
    __syncthreads();

    const int stride = gridDim.x * 256;
    const vfloat4* src4 = (const vfloat4*)src;
    for (int i = blockIdx.x * 256 + tid; i < n4; i += stride) {
        vfloat4 v = __builtin_nontemporal_load(&src4[i]);   // don't pollute L3
        int i0 = quant_idx(v.x);
        int i1 = quant_idx(v.y);
        int i2 = quant_idx(v.z);
        int i3 = quant_idx(v.w);
        atomicAdd(&lh[wave][i0], 1u);
        atomicAdd(&lh[wave][i1], 1u);
        atomicAdd(&lh[wave][i2], 1u);
        atomicAdd(&lh[wave][i3], 1u);
        if (STORE_IDX) {
            unsigned int packed = (unsigned int)i0 | ((unsigned int)i1 << 8) |
                                  ((unsigned int)i2 << 16) | ((unsigned int)i3 << 24);
            idx4_out[i] = packed;   // normal store: want this L3-resident for pass 3
        }
    }
    // tail (n not divisible by 4) — block 0, folded into its LDS hist
    if (blockIdx.x == 0 && tid == 0) {
        for (int j = n4 * 4; j < n; ++j) {
            int b = quant_idx(src[j]);
            atomicAdd(&lh[0][b], 1u);
            if (STORE_IDX) ((unsigned char*)idx4_out)[j] = (unsigned char)b;
        }
    }
    __syncthreads();
    for (int b = tid; b < NBINS; b += 256)
        partial[blockIdx.x * NBINS + b] = lh[0][b] + lh[1][b] + lh[2][b] + lh[3][b];
}

// Pass 1b: one block per bin sums the per-block partials (L2-warm, ~2us).
__global__ __launch_bounds__(256) void reduce_kernel(
    const unsigned int* __restrict__ partial, unsigned int* __restrict__ g_hist,
    int nblk) {
    __shared__ unsigned int sh[256];
    const int b = blockIdx.x;
    const int tid = threadIdx.x;
    unsigned int s = 0;
    for (int i = tid; i < nblk; i += 256) s += partial[i * NBINS + b];
    sh[tid] = s;
    __syncthreads();
    for (int off = 128; off > 0; off >>= 1) {
        if (tid < off) sh[tid] += sh[tid + off];
        __syncthreads();
    }
    if (tid == 0) g_hist[b] = sh[0];
}

// Pass 2: one block, parallel scan + searchsorted -> pre-scaled LUT.
__global__ __launch_bounds__(256) void lut_kernel(
    const unsigned int* __restrict__ g_hist, float* __restrict__ lut) {
    __shared__ float scdf[NBINS];
    __shared__ float ncdf[NBINS];
    __shared__ unsigned int wsum[4];
    const int t = threadIdx.x;

    unsigned int v = g_hist[t];
    // inclusive scan within each 64-lane wave
    for (int d = 1; d < 64; d <<= 1) {
        unsigned int o = __shfl_up(v, d, 64);
        if ((t & 63) >= d) v += o;
    }
    if ((t & 63) == 63) wsum[t >> 6] = v;   // per-wave totals
    __syncthreads();
    unsigned int add = 0;
    for (int w = 0; w < (t >> 6); ++w) add += wsum[w];
    v += add;                               // full inclusive cumsum
    const float total = (float)(wsum[0] + wsum[1] + wsum[2] + wsum[3]);
    scdf[t] = (float)v / total;

    // linspace(-1,1,256); norm.cdf(x,0,0.2) = 0.5*(1+erf(x/(0.2*sqrt(2))))
    float x = ((float)t * 2.0f - 255.0f) / 255.0f;
    float nc = 0.5f * (1.0f + erff(x * 3.5355339059327378f));
    float nc255 = 0.5f * (1.0f + erff(3.5355339059327378f));  // == ncdf at x=1
    ncdf[t] = nc / nc255;
    __syncthreads();

    // searchsorted side='left' == lower_bound
    float sv = scdf[t];
    int lo = 0, hi = NBINS;
    while (lo < hi) {
        int m = (lo + hi) >> 1;
        if (ncdf[m] < sv) lo = m + 1; else hi = m;
    }
    lut[t] = ((float)lo / 255.0f) * 2.0f - 1.0f;   // pre-apply final rescale
}

// Pass 3a: gather via stored u8 indices.
__global__ __launch_bounds__(256) void gather_idx_kernel(
    const unsigned int* __restrict__ idx4, const float* __restrict__ lut,
    vfloat4* __restrict__ out, int n4, int n, float* __restrict__ out_flat) {
    __shared__ float l[NBINS];
    for (int i = threadIdx.x; i < NBINS; i += 256) l[i] = lut[i];
    __syncthreads();
    const int stride = gridDim.x * 256;
    for (int i = blockIdx.x * 256 + threadIdx.x; i < n4; i += stride) {
        unsigned int p = __builtin_nontemporal_load(&idx4[i]);
        vfloat4 o;
        o.x = l[p & 255u];
        o.y = l[(p >> 8) & 255u];
        o.z = l[(p >> 16) & 255u];
        o.w = l[p >> 24];
        __builtin_nontemporal_store(o, &out[i]);
    }
    if (blockIdx.x == 0 && threadIdx.x == 0) {
        const unsigned char* ib = (const unsigned char*)idx4;
        for (int j = n4 * 4; j < n; ++j) out_flat[j] = l[ib[j]];
    }
}

// Pass 3b fallback: recompute idx from source (if ws can't hold idx).
__global__ __launch_bounds__(256) void gather_src_kernel(
    const float* __restrict__ src, const float* __restrict__ lut,
    vfloat4* __restrict__ out, int n4, int n, float* __restrict__ out_flat) {
    __shared__ float l[NBINS];
    for (int i = threadIdx.x; i < NBINS; i += 256) l[i] = lut[i];
    __syncthreads();
    const int stride = gridDim.x * 256;
    const vfloat4* src4 = (const vfloat4*)src;
    for (int i = blockIdx.x * 256 + threadIdx.x; i < n4; i += stride) {
        vfloat4 v = __builtin_nontemporal_load(&src4[i]);
        vfloat4 o;
        o.x = l[quant_idx(v.x)];
        o.y = l[quant_idx(v.y)];
        o.z = l[quant_idx(v.z)];
        o.w = l[quant_idx(v.w)];
        __builtin_nontemporal_store(o, &out[i]);
    }
    if (blockIdx.x == 0 && threadIdx.x == 0) {
        for (int j = n4 * 4; j < n; ++j) out_flat[j] = l[quant_idx(src[j])];
    }
}

extern "C" void kernel_launch(void* const* d_in, const int* in_sizes, int n_in,
                              void* d_out, int out_size, void* d_ws, size_t ws_size,
                              hipStream_t stream) {
    const float* src = (const float*)d_in[0];
    const int n = in_sizes[0];
    const int n4 = n >> 2;

    // ws layout: [0,1KB) g_hist | [1KB,2KB) lut | [4KB, 4KB+1MiB) partials | idx4
    unsigned int* g_hist = (unsigned int*)d_ws;
    float* lut = (float*)((char*)d_ws + 1024);
    unsigned int* partial = (unsigned int*)((char*)d_ws + 4096);
    const size_t idx_off = 4096 + (size_t)HIST_BLOCKS * NBINS * 4;
    unsigned int* idx4 = (unsigned int*)((char*)d_ws + idx_off);
    const bool store_idx = ws_size >= idx_off + (size_t)n;

    const dim3 block(256);
    if (store_idx) {
        hist_kernel<true><<<dim3(HIST_BLOCKS), block, 0, stream>>>(src, partial, idx4, n4, n);
    } else {
        hist_kernel<false><<<dim3(HIST_BLOCKS), block, 0, stream>>>(src, partial, nullptr, n4, n);
    }
    reduce_kernel<<<dim3(NBINS), block, 0, stream>>>(partial, g_hist, HIST_BLOCKS);
    lut_kernel<<<dim3(1), block, 0, stream>>>(g_hist, lut);
    if (store_idx) {
        gather_idx_kernel<<<dim3(2048), block, 0, stream>>>(idx4, lut, (vfloat4*)d_out,
                                                            n4, n, (float*)d_out);
    } else {
        gather_src_kernel<<<dim3(2048), block, 0, stream>>>(src, lut, (vfloat4*)d_out,
                                                            n4, n, (float*)d_out);
    }
}

// Round 4
// 120.919 us; speedup vs baseline: 1.4735x; 1.0589x over previous
//
#include <hip/hip_runtime.h>
#include <math.h>

#define NBINS 256
#define HIST_COPIES 32
#define HIST_BLOCKS 1024
#define GATH_BLOCKS 1024

typedef float vfloat4 __attribute__((ext_vector_type(4)));

__device__ __forceinline__ int quant_idx(float s) {
    // reference: clip(floor((s+1)/2*255), 0, 255)
    float t = floorf((s + 1.0f) * 0.5f * 255.0f);
    t = fminf(fmaxf(t, 0.0f), 255.0f);
    return (int)t;
}

// ---- Pass 1: LDS-privatized histogram -> 32 contention-split global copies,
//      plus packed-u8 idx store (cached: want it L3-resident for pass 2).
template <bool STORE_IDX>
__global__ __launch_bounds__(256) void hist_kernel(
    const float* __restrict__ src, unsigned int* __restrict__ copies,
    unsigned int* __restrict__ idx4_out, int n4, int n) {
    __shared__ unsigned int lh[4][NBINS];
    const int tid = threadIdx.x;
    const int wave = tid >> 6;
    for (int i = tid; i < 4 * NBINS; i += 256) ((unsigned int*)lh)[i] = 0u;
    __syncthreads();

    const int stride = gridDim.x * 256;
    const vfloat4* src4 = (const vfloat4*)src;
    for (int i = blockIdx.x * 256 + tid; i < n4; i += stride) {
        vfloat4 v = __builtin_nontemporal_load(&src4[i]);   // don't pollute L2/L3
        int i0 = quant_idx(v.x);
        int i1 = quant_idx(v.y);
        int i2 = quant_idx(v.z);
        int i3 = quant_idx(v.w);
        atomicAdd(&lh[wave][i0], 1u);
        atomicAdd(&lh[wave][i1], 1u);
        atomicAdd(&lh[wave][i2], 1u);
        atomicAdd(&lh[wave][i3], 1u);
        if (STORE_IDX) {
            idx4_out[i] = (unsigned int)i0 | ((unsigned int)i1 << 8) |
                          ((unsigned int)i2 << 16) | ((unsigned int)i3 << 24);
        }
    }
    // tail (n % 4) — block 0, folded into its LDS hist before the reduction
    if (blockIdx.x == 0 && tid == 0) {
        for (int j = n4 * 4; j < n; ++j) {
            int b = quant_idx(src[j]);
            atomicAdd(&lh[0][b], 1u);
            if (STORE_IDX) ((unsigned char*)idx4_out)[j] = (unsigned char)b;
        }
    }
    __syncthreads();
    // one atomic per bin per block, spread over 32 copies (zeroed by memset)
    unsigned int s = lh[0][tid] + lh[1][tid] + lh[2][tid] + lh[3][tid];
    if (s) atomicAdd(&copies[(blockIdx.x & (HIST_COPIES - 1)) * NBINS + tid], s);
}

// ---- LUT built per-block (redundant, ~1-2us): sum copies -> scan -> normal
//      CDF -> lower_bound -> pre-scaled output value in LDS.
__device__ __forceinline__ void build_lut(
    const unsigned int* __restrict__ copies, float* luts /*LDS[256]*/,
    float* ncdf /*LDS[256]*/, unsigned int* wsum /*LDS[4]*/) {
    const int tid = threadIdx.x;
    const int wave = tid >> 6;
    unsigned int hv = 0;
#pragma unroll
    for (int c = 0; c < HIST_COPIES; ++c) hv += copies[c * NBINS + tid];
    // inclusive scan across 256 threads (wave shfl + wave-total combine)
    unsigned int v = hv;
    for (int d = 1; d < 64; d <<= 1) {
        unsigned int o = __shfl_up(v, d, 64);
        if ((tid & 63) >= d) v += o;
    }
    if ((tid & 63) == 63) wsum[wave] = v;
    __syncthreads();
    unsigned int add = 0;
    for (int w = 0; w < wave; ++w) add += wsum[w];
    v += add;
    const float total = (float)(wsum[0] + wsum[1] + wsum[2] + wsum[3]);
    const float sv = (float)v / total;

    // linspace(-1,1,256); norm.cdf(x,0,0.2) = 0.5*(1+erf(x/(0.2*sqrt(2))))
    const float x = ((float)tid * 2.0f - 255.0f) / 255.0f;
    const float nc = 0.5f * (1.0f + erff(x * 3.5355339059327378f));
    const float nc255 = 0.5f * (1.0f + erff(3.5355339059327378f));
    ncdf[tid] = nc / nc255;
    __syncthreads();
    // searchsorted side='left' == lower_bound
    int lo = 0, hi = NBINS;
    while (lo < hi) {
        int m = (lo + hi) >> 1;
        if (ncdf[m] < sv) lo = m + 1; else hi = m;
    }
    luts[tid] = (float)lo * (2.0f / 255.0f) - 1.0f;   // pre-apply final rescale
    __syncthreads();
}

// ---- Pass 2a: per-block LUT + gather via stored u8 indices.
__global__ __launch_bounds__(256) void gather_idx_kernel(
    const unsigned int* __restrict__ idx4, const unsigned int* __restrict__ copies,
    vfloat4* __restrict__ out, int n4, int n, float* __restrict__ out_flat) {
    __shared__ float luts[NBINS];
    __shared__ float ncdf[NBINS];
    __shared__ unsigned int wsum[4];
    build_lut(copies, luts, ncdf, wsum);

    const int stride = gridDim.x * 256;
    for (int i = blockIdx.x * 256 + threadIdx.x; i < n4; i += stride) {
        unsigned int p = idx4[i];                  // cached load: L3-resident
        vfloat4 o;
        o.x = luts[p & 255u];
        o.y = luts[(p >> 8) & 255u];
        o.z = luts[(p >> 16) & 255u];
        o.w = luts[p >> 24];
        __builtin_nontemporal_store(o, &out[i]);
    }
    if (blockIdx.x == 0 && threadIdx.x == 0) {
        const unsigned char* ib = (const unsigned char*)idx4;
        for (int j = n4 * 4; j < n; ++j) out_flat[j] = luts[ib[j]];
    }
}

// ---- Pass 2b fallback: recompute idx from source (ws too small for idx).
__global__ __launch_bounds__(256) void gather_src_kernel(
    const float* __restrict__ src, const unsigned int* __restrict__ copies,
    vfloat4* __restrict__ out, int n4, int n, float* __restrict__ out_flat) {
    __shared__ float luts[NBINS];
    __shared__ float ncdf[NBINS];
    __shared__ unsigned int wsum[4];
    build_lut(copies, luts, ncdf, wsum);

    const int stride = gridDim.x * 256;
    const vfloat4* src4 = (const vfloat4*)src;
    for (int i = blockIdx.x * 256 + threadIdx.x; i < n4; i += stride) {
        vfloat4 v = __builtin_nontemporal_load(&src4[i]);
        vfloat4 o;
        o.x = luts[quant_idx(v.x)];
        o.y = luts[quant_idx(v.y)];
        o.z = luts[quant_idx(v.z)];
        o.w = luts[quant_idx(v.w)];
        __builtin_nontemporal_store(o, &out[i]);
    }
    if (blockIdx.x == 0 && threadIdx.x == 0) {
        for (int j = n4 * 4; j < n; ++j) out_flat[j] = luts[quant_idx(src[j])];
    }
}

extern "C" void kernel_launch(void* const* d_in, const int* in_sizes, int n_in,
                              void* d_out, int out_size, void* d_ws, size_t ws_size,
                              hipStream_t stream) {
    const float* src = (const float*)d_in[0];
    const int n = in_sizes[0];
    const int n4 = n >> 2;
    const dim3 block(256);

    // ws layout: [0, 32KiB) hist copies | [32KiB, ...) packed u8 idx
    unsigned int* copies = (unsigned int*)d_ws;
    const size_t idx_off = (size_t)HIST_COPIES * NBINS * 4;
    unsigned int* idx4 = (unsigned int*)((char*)d_ws + idx_off);
    const bool store_idx = ws_size >= idx_off + (size_t)n;

    hipMemsetAsync(copies, 0, HIST_COPIES * NBINS * sizeof(unsigned int), stream);

    if (store_idx) {
        hist_kernel<true><<<dim3(HIST_BLOCKS), block, 0, stream>>>(src, copies, idx4, n4, n);
        gather_idx_kernel<<<dim3(GATH_BLOCKS), block, 0, stream>>>(idx4, copies,
                                                                   (vfloat4*)d_out, n4, n,
                                                                   (float*)d_out);
    } else {
        hist_kernel<false><<<dim3(HIST_BLOCKS), block, 0, stream>>>(src, copies, nullptr, n4, n);
        gather_src_kernel<<<dim3(GATH_BLOCKS), block, 0, stream>>>(src, copies,
                                                                   (vfloat4*)d_out, n4, n,
                                                                   (float*)d_out);
    }
}